// Round 3
// baseline (1163.699 us; speedup 1.0000x reference)
//
#include <hip/hip_runtime.h>

namespace {
constexpr int kB = 256;
constexpr int kS = 2048;
constexpr int kV = 10;
constexpr int kE = 32;
constexpr int kH = 64;
constexpr int kO = 10;
constexpr int kT = 16;      // steps per tile (logits batched per tile)
constexpr int kPad = 68;    // LDS row stride in floats (272 B, float4-aligned)
constexpr int kR = 2;       // sequences (rows) per wave — fills LDS-latency stalls

typedef float v2f __attribute__((ext_vector_type(2)));

__device__ __forceinline__ float fast_tanh(float x) {
    float xc = __builtin_amdgcn_fmed3f(x, -9.0f, 9.0f);   // tanh(9)==1 in fp32
    float e  = __expf(2.0f * xc);
    return (e - 1.0f) * __builtin_amdgcn_rcpf(e + 1.0f);
}

__global__ __launch_bounds__(64, 1)
void rnn_fused(const int* __restrict__ num1, const int* __restrict__ num2,
               const float* __restrict__ embed, const float* __restrict__ Wx,
               const float* __restrict__ Wh, const float* __restrict__ bias,
               const float* __restrict__ Wd, const float* __restrict__ bd,
               float* __restrict__ out)
{
    const int row0 = blockIdx.x * kR;   // two sequences per block (single wave)
    const int j    = threadIdx.x;       // lane j owns hidden unit j (both rows)

    __shared__ __align__(16) float TT[kV * kV][kH];     // 100 possible xw rows (weights-only)
    __shared__ __align__(16) float hbuf[kR][kT][kPad];  // h history; also the broadcast medium
    __shared__ __align__(16) float WdT[kO][kPad];
    __shared__ float bdL[kO];

    // ---- one-time per-block setup ----
    {
        float wxc[2 * kE];
        #pragma unroll
        for (int k = 0; k < 2 * kE; ++k) wxc[k] = Wx[k * kH + j];  // Wx column j
        float bj = bias[j];
        float t1[kV], t2[kV];
        #pragma unroll
        for (int v = 0; v < kV; ++v) {
            float a0 = 0.f, a1 = 0.f;
            #pragma unroll
            for (int k = 0; k < kE; ++k) {
                float e = embed[v * kE + k];   // lane-uniform -> s_load
                a0 = fmaf(e, wxc[k], a0);
                a1 = fmaf(e, wxc[kE + k], a1);
            }
            t1[v] = a0; t2[v] = a1;
        }
        #pragma unroll
        for (int v1 = 0; v1 < kV; ++v1)
            #pragma unroll
            for (int v2 = 0; v2 < kV; ++v2)
                TT[v1 * kV + v2][j] = t1[v1] + t2[v2] + bj;
        #pragma unroll
        for (int o = 0; o < kO; ++o) WdT[o][j] = Wd[j * kO + o];
        if (j < kO) bdL[j] = bd[j];
        hbuf[0][kT - 1][j] = 0.f;   // h_{-1} = 0 (step 0 reads slot kT-1)
        hbuf[1][kT - 1][j] = 0.f;
    }

    // Wh column j as float2 pairs for v_pk_fma_f32
    v2f whc2[kH / 2];
    #pragma unroll
    for (int i = 0; i < kH / 2; ++i) {
        whc2[i].x = Wh[(2 * i + 0) * kH + j];
        whc2[i].y = Wh[(2 * i + 1) * kH + j];
    }

    __syncthreads();

    // lanes 0..15 hold row A's 16 step-indices, lanes 16..31 row B's
    int idxv = 0;
    if (j < 32) {
        int r = row0 + (j >> 4);
        int t = j & 15;
        idxv = num1[r * kS + t] * kV + num2[r * kS + t];
    }

    for (int t0 = 0; t0 < kS; t0 += kT) {
        // prefetch next tile's indices (HBM latency hidden under this tile)
        int idx_next = 0;
        if (j < 32 && t0 + kT < kS) {
            int r = row0 + (j >> 4);
            int t = t0 + kT + (j & 15);
            idx_next = num1[r * kS + t] * kV + num2[r * kS + t];
        }

        // prefetch all xw rows for this tile (LDS broadcasts, independent of scan chain)
        float xwA[kT], xwB[kT];
        #pragma unroll
        for (int tl = 0; tl < kT; ++tl) {
            int sA = __builtin_amdgcn_readlane(idxv, tl);        // uniform
            int sB = __builtin_amdgcn_readlane(idxv, 16 + tl);   // uniform
            xwA[tl] = TT[sA][j];
            xwB[tl] = TT[sB][j];
        }

        // ---- 16 sequential recurrence steps, two independent rows interleaved ----
        #pragma unroll
        for (int tl = 0; tl < kT; ++tl) {
            const int prev = (tl + kT - 1) & (kT - 1);
            const float4* pA = reinterpret_cast<const float4*>(&hbuf[0][prev][0]);
            const float4* pB = reinterpret_cast<const float4*>(&hbuf[1][prev][0]);
            v2f aA[4] = {{xwA[tl], 0.f}, {0.f, 0.f}, {0.f, 0.f}, {0.f, 0.f}};
            v2f aB[4] = {{xwB[tl], 0.f}, {0.f, 0.f}, {0.f, 0.f}, {0.f, 0.f}};
            #pragma unroll
            for (int c = 0; c < kH / 4; ++c) {
                float4 qA = pA[c];              // all lanes same addr -> broadcast
                float4 qB = pB[c];
                v2f hA0 = {qA.x, qA.y}, hA1 = {qA.z, qA.w};
                v2f hB0 = {qB.x, qB.y}, hB1 = {qB.z, qB.w};
                int s = (c & 1) * 2;            // 8 accumulator chains total
                aA[s + 0] = __builtin_elementwise_fma(hA0, whc2[2 * c + 0], aA[s + 0]);
                aA[s + 1] = __builtin_elementwise_fma(hA1, whc2[2 * c + 1], aA[s + 1]);
                aB[s + 0] = __builtin_elementwise_fma(hB0, whc2[2 * c + 0], aB[s + 0]);
                aB[s + 1] = __builtin_elementwise_fma(hB1, whc2[2 * c + 1], aB[s + 1]);
            }
            v2f sA2 = (aA[0] + aA[1]) + (aA[2] + aA[3]);
            v2f sB2 = (aB[0] + aB[1]) + (aB[2] + aB[3]);
            float hA = fast_tanh(sA2.x + sA2.y);   // two tanh chains overlap
            float hB = fast_tanh(sB2.x + sB2.y);
            hbuf[0][tl][j] = hA;   // same-wave DS ops execute in order:
            hbuf[1][tl][j] = hB;   // next step's broadcast reads see these
        }
        __syncthreads();

        // ---- batched logits: 320 outputs (2 rows x 16 steps x 10) over 64 lanes ----
        const int obase0 = row0 * (kS * kO) + t0 * kO;
        #pragma unroll
        for (int r = 0; r < 5; ++r) {
            int f = r * 64 + j;                    // 5*64 == 320 exactly, no guard
            int rowSel = f / 160;
            int rem = f - rowSel * 160;
            int tl = rem / 10;
            int o  = rem - tl * 10;
            const float4* hb4 = reinterpret_cast<const float4*>(&hbuf[rowSel][tl][0]);
            const float4* wd4 = reinterpret_cast<const float4*>(&WdT[o][0]);
            float a0 = bdL[o], a1 = 0.f, a2 = 0.f, a3 = 0.f;
            #pragma unroll
            for (int c = 0; c < kH / 4; ++c) {
                float4 h4 = hb4[c];
                float4 w4 = wd4[c];
                a0 = fmaf(h4.x, w4.x, a0);
                a1 = fmaf(h4.y, w4.y, a1);
                a2 = fmaf(h4.z, w4.z, a2);
                a3 = fmaf(h4.w, w4.w, a3);
            }
            out[obase0 + rowSel * (kS * kO) + tl * kO + o] = (a0 + a1) + (a2 + a3);
        }
        __syncthreads();
        idxv = idx_next;
    }
}
} // namespace

extern "C" void kernel_launch(void* const* d_in, const int* in_sizes, int n_in,
                              void* d_out, int out_size, void* d_ws, size_t ws_size,
                              hipStream_t stream) {
    (void)in_sizes; (void)n_in; (void)d_ws; (void)ws_size; (void)out_size;
    rnn_fused<<<dim3(kB / kR), dim3(64), 0, stream>>>(
        (const int*)d_in[0], (const int*)d_in[1],
        (const float*)d_in[2], (const float*)d_in[3],
        (const float*)d_in[4], (const float*)d_in[5],
        (const float*)d_in[6], (const float*)d_in[7],
        (float*)d_out);
}

// Round 4
// 875.747 us; speedup vs baseline: 1.3288x; 1.3288x over previous
//
#include <hip/hip_runtime.h>

namespace {
constexpr int kB = 256;
constexpr int kS = 2048;
constexpr int kV = 10;
constexpr int kE = 32;
constexpr int kH = 64;
constexpr int kO = 10;
constexpr int kT = 16;      // steps per tile (logits batched per tile)
constexpr int kPad = 68;    // LDS row stride in floats (272 B, 16B-aligned)
// Fold tanh's 2x AND exp's log2(e) into the weights: s = kC*(xw + h.Wh + b)
// then e^{2*preact} == 2^s == v_exp_f32(s). Saves 2 muls from the serial chain.
constexpr float kC = 2.885390081777927f;   // 2*log2(e)

__global__ __launch_bounds__(64, 1)
void rnn_fused(const int* __restrict__ num1, const int* __restrict__ num2,
               const float* __restrict__ embed, const float* __restrict__ Wx,
               const float* __restrict__ Wh, const float* __restrict__ bias,
               const float* __restrict__ Wd, const float* __restrict__ bd,
               float* __restrict__ out)
{
    const int row = blockIdx.x;   // one sequence per block (single wave)
    const int j   = threadIdx.x;  // lane j owns hidden unit j

    __shared__ __align__(16) float TT[kV * kV][kH];   // kC*(xw+b) for 100 pairs
    __shared__ __align__(16) float hbuf[kT][kPad];    // h history + broadcast medium
    __shared__ __align__(16) float WdT[kO][kPad];
    __shared__ float bdL[kO];

    // ---- one-time per-block setup ----
    {
        float wxc[2 * kE];
        #pragma unroll
        for (int k = 0; k < 2 * kE; ++k) wxc[k] = Wx[k * kH + j];  // Wx column j
        float bj = bias[j];
        float t1[kV], t2[kV];
        #pragma unroll
        for (int v = 0; v < kV; ++v) {
            float a0 = 0.f, a1 = 0.f;
            #pragma unroll
            for (int k = 0; k < kE; ++k) {
                float e = embed[v * kE + k];   // lane-uniform -> s_load
                a0 = fmaf(e, wxc[k], a0);
                a1 = fmaf(e, wxc[kE + k], a1);
            }
            t1[v] = a0; t2[v] = a1;
        }
        #pragma unroll
        for (int v1 = 0; v1 < kV; ++v1)
            #pragma unroll
            for (int v2 = 0; v2 < kV; ++v2)
                TT[v1 * kV + v2][j] = kC * (t1[v1] + t2[v2] + bj);
        #pragma unroll
        for (int o = 0; o < kO; ++o) WdT[o][j] = Wd[j * kO + o];
        if (j < kO) bdL[j] = bd[j];
        hbuf[kT - 1][j] = 0.f;     // h_{-1} = 0 (step 0 reads slot kT-1)
    }

    float whc[kH];                 // kC * Wh column j
    #pragma unroll
    for (int i = 0; i < kH; ++i) whc[i] = kC * Wh[i * kH + j];

    __syncthreads();

    const int lane16 = j & 15;
    const int nb = row * kS;
    int idxv = num1[nb + lane16] * kV + num2[nb + lane16];

    for (int t0 = 0; t0 < kS; t0 += kT) {
        // prefetch next tile's indices (HBM latency hidden under this tile)
        int idx_next = 0;
        if (t0 + kT < kS) {
            int tt = nb + t0 + kT + lane16;
            idx_next = num1[tt] * kV + num2[tt];
        }

        // prefetch all 16 scaled-xw rows for this tile
        float xw[kT];
        #pragma unroll
        for (int tl = 0; tl < kT; ++tl) {
            int sidx = __builtin_amdgcn_readlane(idxv, tl);   // uniform
            xw[tl] = TT[sidx][j];
        }

        // ---- 16 sequential recurrence steps ----
        #pragma unroll
        for (int tl = 0; tl < kT; ++tl) {
            const int prev = (tl + kT - 1) & (kT - 1);
            // all lanes read the SAME addresses -> conflict-free broadcast;
            // scalar FMAs consume the b128 quads directly (no repacking)
            const float4* hp = reinterpret_cast<const float4*>(&hbuf[prev][0]);
            float a0 = xw[tl], a1 = 0.f, a2 = 0.f, a3 = 0.f;
            #pragma unroll
            for (int c = 0; c < kH / 4; ++c) {
                float4 q = hp[c];
                a0 = fmaf(q.x, whc[4 * c + 0], a0);
                a1 = fmaf(q.y, whc[4 * c + 1], a1);
                a2 = fmaf(q.z, whc[4 * c + 2], a2);
                a3 = fmaf(q.w, whc[4 * c + 3], a3);
            }
            float s = (a0 + a1) + (a2 + a3);            // s = 2*log2e*preact
            s = __builtin_amdgcn_fmed3f(s, -26.f, 26.f); // tanh(|9|)==1 in fp32
            float e = __builtin_amdgcn_exp2f(s);        // e^{2*preact}
            float r = __builtin_amdgcn_rcpf(e + 1.f);
            float hv = fmaf(-2.f, r, 1.f);              // tanh = 1 - 2/(e+1)
            hbuf[tl][j] = hv;    // same-wave DS ops are in-order: next step's
                                 // broadcast reads see this write
        }
        __syncthreads();

        // ---- batched logits for the tile: 160 outputs over 64 lanes ----
        const int obase = row * (kS * kO) + t0 * kO;
        #pragma unroll
        for (int r = 0; r < 3; ++r) {
            int f = r * 64 + j;                  // flat (t_local, o) index
            if (f < kT * kO) {
                int tl = f / kO;
                int o  = f - tl * kO;
                const float4* hb4 = reinterpret_cast<const float4*>(&hbuf[tl][0]);
                const float4* wd4 = reinterpret_cast<const float4*>(&WdT[o][0]);
                float a0 = bdL[o], a1 = 0.f, a2 = 0.f, a3 = 0.f;
                #pragma unroll
                for (int c = 0; c < kH / 4; ++c) {
                    float4 h4 = hb4[c];
                    float4 w4 = wd4[c];
                    a0 = fmaf(h4.x, w4.x, a0);
                    a1 = fmaf(h4.y, w4.y, a1);
                    a2 = fmaf(h4.z, w4.z, a2);
                    a3 = fmaf(h4.w, w4.w, a3);
                }
                out[obase + f] = (a0 + a1) + (a2 + a3);   // coalesced
            }
        }
        __syncthreads();
        idxv = idx_next;
    }
}
} // namespace

extern "C" void kernel_launch(void* const* d_in, const int* in_sizes, int n_in,
                              void* d_out, int out_size, void* d_ws, size_t ws_size,
                              hipStream_t stream) {
    (void)in_sizes; (void)n_in; (void)d_ws; (void)ws_size; (void)out_size;
    rnn_fused<<<dim3(kB), dim3(64), 0, stream>>>(
        (const int*)d_in[0], (const int*)d_in[1],
        (const float*)d_in[2], (const float*)d_in[3],
        (const float*)d_in[4], (const float*)d_in[5],
        (const float*)d_in[6], (const float*)d_in[7],
        (float*)d_out);
}

// Round 5
// 712.156 us; speedup vs baseline: 1.6341x; 1.2297x over previous
//
#include <hip/hip_runtime.h>

namespace {
constexpr int kB = 256;
constexpr int kS = 2048;
constexpr int kV = 10;
constexpr int kE = 32;
constexpr int kH = 64;
constexpr int kO = 10;
constexpr int kT = 16;      // steps per tile
constexpr int kPad = 68;    // LDS row stride in floats (272 B, 16B-aligned)
// Fold tanh's 2x and log2(e) into weights: s = kC*(xw + h.Wh + b), e^{2p} = 2^s
constexpr float kC = 2.885390081777927f;   // 2*log2(e)

__device__ __forceinline__ float step_tanh(float s) {
    s = __builtin_amdgcn_fmed3f(s, -26.f, 26.f);
    float e = __builtin_amdgcn_exp2f(s);
    float r = __builtin_amdgcn_rcpf(e + 1.f);
    return fmaf(-2.f, r, 1.f);              // tanh = 1 - 2/(e^{2p}+1)
}

// 16 recurrence steps. hbufPrevLast = h of the previous tile's last step.
__device__ __forceinline__ void do_steps(float* __restrict__ cur,
                                         const float* __restrict__ prevLast,
                                         const float* __restrict__ xw,
                                         const float* __restrict__ whc, int j)
{
    #pragma unroll
    for (int tl = 0; tl < kT; ++tl) {
        const float4* hp = (tl == 0)
            ? reinterpret_cast<const float4*>(prevLast)
            : reinterpret_cast<const float4*>(cur + (tl - 1) * kPad);
        // Batch ALL 16 broadcast reads into live registers so the DS pipe
        // streams them (~12 cy apiece) instead of 16 serial round-trips.
        // (R3 had VGPR_Count=88 -> only 1 quad in flight -> ~900 cy/step.)
        float4 q[kH / 4];
        #pragma unroll
        for (int c = 0; c < kH / 4; ++c) q[c] = hp[c];
        __builtin_amdgcn_sched_barrier(0);   // keep loads batched ahead of FMAs
        float a0 = xw[tl], a1 = 0.f, a2 = 0.f, a3 = 0.f;
        #pragma unroll
        for (int c = 0; c < kH / 4; ++c) {
            a0 = fmaf(q[c].x, whc[4 * c + 0], a0);
            a1 = fmaf(q[c].y, whc[4 * c + 1], a1);
            a2 = fmaf(q[c].z, whc[4 * c + 2], a2);
            a3 = fmaf(q[c].w, whc[4 * c + 3], a3);
        }
        cur[tl * kPad + j] = step_tanh((a0 + a1) + (a2 + a3));
        // single wave: DS pipe is in-order; next step's reads see this write
    }
}

__device__ __forceinline__ void do_logits(const float* __restrict__ hb,
                                          const float (* __restrict__ WdT)[kPad],
                                          const float* __restrict__ bdL,
                                          float* __restrict__ out, int obase, int j)
{
    #pragma unroll
    for (int r = 0; r < 3; ++r) {
        int f = r * 64 + j;                  // flat (t_local, o), 160 total
        if (f < kT * kO) {
            int tl = f / kO;
            int o  = f - tl * kO;
            const float4* hb4 = reinterpret_cast<const float4*>(hb + tl * kPad);
            const float4* wd4 = reinterpret_cast<const float4*>(&WdT[o][0]);
            float a0 = bdL[o], a1 = 0.f, a2 = 0.f, a3 = 0.f;
            #pragma unroll
            for (int c = 0; c < kH / 4; ++c) {
                float4 h4 = hb4[c];
                float4 w4 = wd4[c];
                a0 = fmaf(h4.x, w4.x, a0);
                a1 = fmaf(h4.y, w4.y, a1);
                a2 = fmaf(h4.z, w4.z, a2);
                a3 = fmaf(h4.w, w4.w, a3);
            }
            out[obase + f] = (a0 + a1) + (a2 + a3);   // coalesced
        }
    }
}

__global__ __launch_bounds__(64, 1)
void rnn_fused(const int* __restrict__ num1, const int* __restrict__ num2,
               const float* __restrict__ embed, const float* __restrict__ Wx,
               const float* __restrict__ Wh, const float* __restrict__ bias,
               const float* __restrict__ Wd, const float* __restrict__ bd,
               float* __restrict__ out)
{
    const int row = blockIdx.x;   // one sequence per block (single wave)
    const int j   = threadIdx.x;  // lane j owns hidden unit j

    __shared__ __align__(16) float TT[kV * kV][kH];     // kC*(xw+b), 100 rows
    __shared__ __align__(16) float hbuf[2][kT][kPad];   // double-buffered h history
    __shared__ __align__(16) float WdT[kO][kPad];
    __shared__ float bdL[kO];

    // ---- one-time per-block setup (single wave: no barriers needed) ----
    {
        float wxc[2 * kE];
        #pragma unroll
        for (int k = 0; k < 2 * kE; ++k) wxc[k] = Wx[k * kH + j];  // Wx column j
        float bj = bias[j];
        float t1[kV], t2[kV];
        #pragma unroll
        for (int v = 0; v < kV; ++v) {
            float a0 = 0.f, a1 = 0.f;
            #pragma unroll
            for (int k = 0; k < kE; ++k) {
                float e = embed[v * kE + k];   // lane-uniform -> s_load
                a0 = fmaf(e, wxc[k], a0);
                a1 = fmaf(e, wxc[kE + k], a1);
            }
            t1[v] = a0; t2[v] = a1;
        }
        #pragma unroll
        for (int v1 = 0; v1 < kV; ++v1)
            #pragma unroll
            for (int v2 = 0; v2 < kV; ++v2)
                TT[v1 * kV + v2][j] = kC * (t1[v1] + t2[v2] + bj);
        #pragma unroll
        for (int o = 0; o < kO; ++o) WdT[o][j] = Wd[j * kO + o];
        if (j < kO) bdL[j] = bd[j];
        hbuf[1][kT - 1][j] = 0.f;   // h_{-1}=0: tile 0 (buf 0) reads buf1 row 15
    }

    float whc[kH];                 // kC * Wh column j
    #pragma unroll
    for (int i = 0; i < kH; ++i) whc[i] = kC * Wh[i * kH + j];

    const int lane16 = j & 15;
    const int nb = row * kS;
    const int orow = row * (kS * kO);

    // tile-0 peel
    int idxv = num1[nb + lane16] * kV + num2[nb + lane16];
    float xw[kT];
    #pragma unroll
    for (int tl = 0; tl < kT; ++tl) {
        int sidx = __builtin_amdgcn_readlane(idxv, tl);   // uniform
        xw[tl] = TT[sidx][j];
    }
    int idx_next = num1[nb + kT + lane16] * kV + num2[nb + kT + lane16];
    do_steps(&hbuf[0][0][0], &hbuf[1][kT - 1][0], xw, whc, j);

    int b = 0;
    for (int t0 = kT; t0 < kS; t0 += kT) {
        idxv = idx_next;
        if (t0 + kT < kS) {
            int tt = nb + t0 + kT + lane16;
            idx_next = num1[tt] * kV + num2[tt];
        }
        #pragma unroll
        for (int tl = 0; tl < kT; ++tl) {
            int sidx = __builtin_amdgcn_readlane(idxv, tl);
            xw[tl] = TT[sidx][j];
        }
        int nbuf = b ^ 1;
        // logits of the PREVIOUS tile (independent of this tile's steps):
        // placed before steps so the scheduler can overlap with the load window
        do_steps(&hbuf[nbuf][0][0], &hbuf[b][kT - 1][0], xw, whc, j);
        do_logits(&hbuf[b][0][0], WdT, bdL, out, orow + (t0 - kT) * kO, j);
        b = nbuf;
    }
    do_logits(&hbuf[b][0][0], WdT, bdL, out, orow + (kS - kT) * kO, j);
}
} // namespace

extern "C" void kernel_launch(void* const* d_in, const int* in_sizes, int n_in,
                              void* d_out, int out_size, void* d_ws, size_t ws_size,
                              hipStream_t stream) {
    (void)in_sizes; (void)n_in; (void)d_ws; (void)ws_size; (void)out_size;
    rnn_fused<<<dim3(kB), dim3(64), 0, stream>>>(
        (const int*)d_in[0], (const int*)d_in[1],
        (const float*)d_in[2], (const float*)d_in[3],
        (const float*)d_in[4], (const float*)d_in[5],
        (const float*)d_in[6], (const float*)d_in[7],
        (float*)d_out);
}

// Round 6
// 701.363 us; speedup vs baseline: 1.6592x; 1.0154x over previous
//
#include <hip/hip_runtime.h>

namespace {
constexpr int kB = 256;
constexpr int kS = 2048;
constexpr int kV = 10;
constexpr int kE = 32;
constexpr int kH = 64;
constexpr int kO = 10;
constexpr int kT = 16;      // steps per tile
constexpr int kPad = 68;    // LDS row stride in floats (272 B, 16B-aligned)
// Fold tanh's 2x and log2(e) into weights: s = kC*(xw + h.Wh + b), e^{2p} = 2^s
constexpr float kC = 2.885390081777927f;   // 2*log2(e)

__device__ __forceinline__ float step_tanh(float s) {
    s = __builtin_amdgcn_fmed3f(s, -26.f, 26.f);
    float e = __builtin_amdgcn_exp2f(s);
    float r = __builtin_amdgcn_rcpf(e + 1.f);
    return fmaf(-2.f, r, 1.f);              // tanh = 1 - 2/(e^{2p}+1)
}

// 16 recurrence steps, split-K partner scheme:
// lane j reads only h[kbase..kbase+31] (8 quads), accumulates that k-half for
// output j (pA, incl. xw) and for partner output j^32 (pB); one shfl combines.
// Halves DS volume AND keeps the in-flight quad batch within the reg budget
// (R4: 16 quads -> allocator split the batch at VGPR_Count=132).
__device__ __forceinline__ void do_steps(float* __restrict__ cur,
                                         const float* __restrict__ prevLast,
                                         const float* __restrict__ xw,
                                         const float* __restrict__ whcA,
                                         const float* __restrict__ whcB,
                                         int j, int kbase)
{
    #pragma unroll
    for (int tl = 0; tl < kT; ++tl) {
        const float* hrow = (tl == 0) ? prevLast : (cur + (tl - 1) * kPad);
        const float4* hp = reinterpret_cast<const float4*>(hrow + kbase);
        float4 q[8];
        #pragma unroll
        for (int c = 0; c < 8; ++c) q[c] = hp[c];   // batched: stream in DS pipe
        __builtin_amdgcn_sched_barrier(0);          // keep loads ahead of FMAs
        float aA0 = xw[tl], aA1 = 0.f, aA2 = 0.f, aA3 = 0.f;
        float aB0 = 0.f,    aB1 = 0.f, aB2 = 0.f, aB3 = 0.f;
        #pragma unroll
        for (int c = 0; c < 8; ++c) {
            aA0 = fmaf(q[c].x, whcA[4 * c + 0], aA0);
            aA1 = fmaf(q[c].y, whcA[4 * c + 1], aA1);
            aA2 = fmaf(q[c].z, whcA[4 * c + 2], aA2);
            aA3 = fmaf(q[c].w, whcA[4 * c + 3], aA3);
            aB0 = fmaf(q[c].x, whcB[4 * c + 0], aB0);
            aB1 = fmaf(q[c].y, whcB[4 * c + 1], aB1);
            aB2 = fmaf(q[c].z, whcB[4 * c + 2], aB2);
            aB3 = fmaf(q[c].w, whcB[4 * c + 3], aB3);
        }
        float pA = (aA0 + aA1) + (aA2 + aA3);       // own output, own k-half
        float pB = (aB0 + aB1) + (aB2 + aB3);       // partner output, own k-half
        float other = __shfl(pB, j ^ 32, 64);       // partner's half of MY output
        cur[tl * kPad + j] = step_tanh(pA + other);
        // single wave: DS pipe is in-order; next step's reads see this write
    }
}

__device__ __forceinline__ void do_logits(const float* __restrict__ hb,
                                          const float (* __restrict__ WdT)[kPad],
                                          const float* __restrict__ bdL,
                                          float* __restrict__ out, int obase, int j)
{
    #pragma unroll
    for (int r = 0; r < 3; ++r) {
        int f = r * 64 + j;                  // flat (t_local, o), 160 total
        if (f < kT * kO) {
            int tl = f / kO;
            int o  = f - tl * kO;
            const float4* hb4 = reinterpret_cast<const float4*>(hb + tl * kPad);
            const float4* wd4 = reinterpret_cast<const float4*>(&WdT[o][0]);
            float a0 = bdL[o], a1 = 0.f, a2 = 0.f, a3 = 0.f;
            #pragma unroll
            for (int c = 0; c < kH / 4; ++c) {
                float4 h4 = hb4[c];
                float4 w4 = wd4[c];
                a0 = fmaf(h4.x, w4.x, a0);
                a1 = fmaf(h4.y, w4.y, a1);
                a2 = fmaf(h4.z, w4.z, a2);
                a3 = fmaf(h4.w, w4.w, a3);
            }
            out[obase + f] = (a0 + a1) + (a2 + a3);   // coalesced
        }
    }
}

__global__ __launch_bounds__(64, 1)
void rnn_fused(const int* __restrict__ num1, const int* __restrict__ num2,
               const float* __restrict__ embed, const float* __restrict__ Wx,
               const float* __restrict__ Wh, const float* __restrict__ bias,
               const float* __restrict__ Wd, const float* __restrict__ bd,
               float* __restrict__ out)
{
    const int row = blockIdx.x;   // one sequence per block (single wave)
    const int j   = threadIdx.x;  // lane j owns hidden unit j
    const int kbase = (j >> 5) * 32;   // this lane's k-half

    __shared__ __align__(16) float TT[kV * kV][kH];     // kC*(xw+b), 100 rows
    __shared__ __align__(16) float hbuf[2][kT][kPad];   // double-buffered h history
    __shared__ __align__(16) float WdT[kO][kPad];
    __shared__ float bdL[kO];

    // ---- one-time per-block setup (single wave: no barriers needed) ----
    {
        float wxc[2 * kE];
        #pragma unroll
        for (int k = 0; k < 2 * kE; ++k) wxc[k] = Wx[k * kH + j];  // Wx column j
        float bj = bias[j];
        float t1[kV], t2[kV];
        #pragma unroll
        for (int v = 0; v < kV; ++v) {
            float a0 = 0.f, a1 = 0.f;
            #pragma unroll
            for (int k = 0; k < kE; ++k) {
                float e = embed[v * kE + k];   // lane-uniform -> s_load
                a0 = fmaf(e, wxc[k], a0);
                a1 = fmaf(e, wxc[kE + k], a1);
            }
            t1[v] = a0; t2[v] = a1;
        }
        #pragma unroll
        for (int v1 = 0; v1 < kV; ++v1)
            #pragma unroll
            for (int v2 = 0; v2 < kV; ++v2)
                TT[v1 * kV + v2][j] = kC * (t1[v1] + t2[v2] + bj);
        #pragma unroll
        for (int o = 0; o < kO; ++o) WdT[o][j] = Wd[j * kO + o];
        if (j < kO) bdL[j] = bd[j];
        hbuf[1][kT - 1][j] = 0.f;   // h_{-1}=0: tile 0 (buf 0) reads buf1 row 15
    }

    // kC * Wh k-half columns: whcA -> own output j, whcB -> partner output j^32
    float whcA[kH / 2], whcB[kH / 2];
    #pragma unroll
    for (int i = 0; i < kH / 2; ++i) {
        whcA[i] = kC * Wh[(kbase + i) * kH + j];
        whcB[i] = kC * Wh[(kbase + i) * kH + (j ^ 32)];
    }

    const int lane16 = j & 15;
    const int nb = row * kS;
    const int orow = row * (kS * kO);

    // tile-0 peel
    int idxv = num1[nb + lane16] * kV + num2[nb + lane16];
    float xw[kT];
    #pragma unroll
    for (int tl = 0; tl < kT; ++tl) {
        int sidx = __builtin_amdgcn_readlane(idxv, tl);   // uniform
        xw[tl] = TT[sidx][j];
    }
    int idx_next = num1[nb + kT + lane16] * kV + num2[nb + kT + lane16];
    do_steps(&hbuf[0][0][0], &hbuf[1][kT - 1][0], xw, whcA, whcB, j, kbase);

    int b = 0;
    for (int t0 = kT; t0 < kS; t0 += kT) {
        idxv = idx_next;
        if (t0 + kT < kS) {
            int tt = nb + t0 + kT + lane16;
            idx_next = num1[tt] * kV + num2[tt];
        }
        #pragma unroll
        for (int tl = 0; tl < kT; ++tl) {
            int sidx = __builtin_amdgcn_readlane(idxv, tl);
            xw[tl] = TT[sidx][j];
        }
        int nbuf = b ^ 1;
        // previous tile's logits are independent of this tile's steps; the
        // scheduler overlaps them with the step chain's stall windows
        do_steps(&hbuf[nbuf][0][0], &hbuf[b][kT - 1][0], xw, whcA, whcB, j, kbase);
        do_logits(&hbuf[b][0][0], WdT, bdL, out, orow + (t0 - kT) * kO, j);
        b = nbuf;
    }
    do_logits(&hbuf[b][0][0], WdT, bdL, out, orow + (kS - kT) * kO, j);
}
} // namespace

extern "C" void kernel_launch(void* const* d_in, const int* in_sizes, int n_in,
                              void* d_out, int out_size, void* d_ws, size_t ws_size,
                              hipStream_t stream) {
    (void)in_sizes; (void)n_in; (void)d_ws; (void)ws_size; (void)out_size;
    rnn_fused<<<dim3(kB), dim3(64), 0, stream>>>(
        (const int*)d_in[0], (const int*)d_in[1],
        (const float*)d_in[2], (const float*)d_in[3],
        (const float*)d_in[4], (const float*)d_in[5],
        (const float*)d_in[6], (const float*)d_in[7],
        (float*)d_out);
}